// Round 16
// baseline (817.669 us; speedup 1.0000x reference)
//
#include <hip/hip_runtime.h>

typedef unsigned short u16;
typedef unsigned int u32;
typedef __attribute__((ext_vector_type(8))) short short8;
typedef __attribute__((ext_vector_type(4))) float f32x4;
typedef __attribute__((ext_vector_type(4))) unsigned int u32x4;

// Problem constants: B=16, N=256, T=4096, D=1024, H=8, DH=128
#define SCALE 0.08838834764831845f
#define OUT_ELEMS 33554432ull  // 16*256*8*1024

__device__ __forceinline__ u16 f2b(float f) {  // f32 -> bf16 RNE
  u32 u = __float_as_uint(f);
  u32 r = u + 0x7fffu + ((u >> 16) & 1u);
  return (u16)(r >> 16);
}

__device__ __forceinline__ u32 cvtpk(float lo, float hi) {  // 2 f32 -> packed bf16x2 (RNE)
  u32 r;
  asm("v_cvt_pk_bf16_f32 %0, %1, %2" : "=v"(r) : "v"(lo), "v"(hi));
  return r;
}

__device__ __forceinline__ void gload16(const void* g, void* l) {
  // async global->LDS, 16B per lane; LDS dest = wave-uniform base (+ lane*16 by HW)
  __builtin_amdgcn_global_load_lds((const __attribute__((address_space(1))) void*)g,
                                   (__attribute__((address_space(3))) void*)l, 16, 0, 0);
}

__device__ __forceinline__ uint2 shflx2(uint2 v, int m) {
  uint2 r;
  r.x = __shfl_xor(v.x, m, 64);
  r.y = __shfl_xor(v.y, m, 64);
  return r;
}

// ---------------- LayerNorm rows of length 1024 -> bf16 (scale folded) -------
__global__ __launch_bounds__(256) void ln_rows(const float* __restrict__ in,
                                               const float* __restrict__ gamma,
                                               u16* __restrict__ out, float scale) {
  const int row = blockIdx.x;
  const int t = threadIdx.x;
  const float4 v = *(const float4*)(in + (size_t)row * 1024 + t * 4);
  float s = v.x + v.y + v.z + v.w;
  float q = v.x * v.x + v.y * v.y + v.z * v.z + v.w * v.w;
#pragma unroll
  for (int m = 32; m; m >>= 1) {
    s += __shfl_down(s, m);
    q += __shfl_down(q, m);
  }
  __shared__ float red[8];
  const int w = t >> 6;
  if ((t & 63) == 0) { red[w] = s; red[4 + w] = q; }
  __syncthreads();
  s = red[0] + red[1] + red[2] + red[3];
  q = red[4] + red[5] + red[6] + red[7];
  const float mu = s * (1.0f / 1024.0f);
  const float var = q * (1.0f / 1024.0f) - mu * mu;
  const float rs = rsqrtf(var + 1e-5f) * scale;
  const float4 g = *(const float4*)(gamma + t * 4);
  ushort4 o;
  o.x = f2b((v.x - mu) * rs * g.x);
  o.y = f2b((v.y - mu) * rs * g.y);
  o.z = f2b((v.z - mu) * rs * g.z);
  o.w = f2b((v.w - mu) * rs * g.w);
  *(ushort4*)(out + (size_t)row * 1024 + t * 4) = o;
}

// ---------------- fused LN(x) + transpose: x -> xn (row-major) + xnt ---------
__global__ __launch_bounds__(1024) void ln_xpose(const float* __restrict__ in,
                                                 const float* __restrict__ gamma,
                                                 u16* __restrict__ xn,
                                                 u16* __restrict__ xnt) {
  __shared__ u16 tile[32][1024];  // 64KB; read side banks 2-way (free)
  const int blk = blockIdx.x;     // 2048 blocks
  const int b = blk >> 7;         // 128 blocks per batch
  const int jj0 = (blk & 127) * 32;
  const int t = threadIdx.x;
  const int lane = t & 63, w = t >> 6;
  const size_t j0 = (size_t)blk * 32;

  float4 gv[4];
#pragma unroll
  for (int k = 0; k < 4; ++k) gv[k] = *(const float4*)(gamma + k * 256 + lane * 4);

  float4 va[2][4];
  float mu[2], rs[2];
#pragma unroll
  for (int rr = 0; rr < 2; ++rr) {
    const int row = w * 2 + rr;
    const float* src = in + (j0 + row) * 1024;
    float s = 0.f, q = 0.f;
#pragma unroll
    for (int k = 0; k < 4; ++k) {
      const float4 v = *(const float4*)(src + k * 256 + lane * 4);
      va[rr][k] = v;
      s += v.x + v.y + v.z + v.w;
      q += v.x * v.x + v.y * v.y + v.z * v.z + v.w * v.w;
    }
#pragma unroll
    for (int m = 1; m < 64; m <<= 1) {
      s += __shfl_xor(s, m);
      q += __shfl_xor(q, m);
    }
    const float m_ = s * (1.0f / 1024.0f);
    mu[rr] = m_;
    rs[rr] = rsqrtf(q * (1.0f / 1024.0f) - m_ * m_ + 1e-5f);
  }
#pragma unroll
  for (int rr = 0; rr < 2; ++rr) {
    const int row = w * 2 + rr;
    u16* xrow = xn + (j0 + row) * 1024;
#pragma unroll
    for (int k = 0; k < 4; ++k) {
      const float4 v = va[rr][k];
      uint2 p;
      p.x = cvtpk((v.x - mu[rr]) * rs[rr] * gv[k].x, (v.y - mu[rr]) * rs[rr] * gv[k].y);
      p.y = cvtpk((v.z - mu[rr]) * rs[rr] * gv[k].z, (v.w - mu[rr]) * rs[rr] * gv[k].w);
      *(uint2*)(xrow + k * 256 + lane * 4) = p;
      *(uint2*)(&tile[row][k * 256 + lane * 4]) = p;
    }
  }
  __syncthreads();
  u32 o[16];
#pragma unroll
  for (int r = 0; r < 16; ++r)
    o[r] = (u32)tile[2 * r][t] | ((u32)tile[2 * r + 1][t] << 16);
  u16* dst = xnt + ((size_t)b * 1024 + t) * 4096 + jj0;
#pragma unroll
  for (int k = 0; k < 4; ++k) {
    u32x4 v = {o[4 * k + 0], o[4 * k + 1], o[4 * k + 2], o[4 * k + 3]};
    *(u32x4*)(dst + k * 8) = v;
  }
}

// ---------------- W_kv[:, :128] -> Wt bf16 [128][1024] -----------------------
__global__ __launch_bounds__(256) void cvt_w(const float* __restrict__ w, u16* __restrict__ wt) {
  const int n = blockIdx.x;  // 0..127
  const int t = threadIdx.x;
  const int d = t * 4;
  ushort4 o;
  o.x = f2b(w[(size_t)(d + 0) * 256 + n]);
  o.y = f2b(w[(size_t)(d + 1) * 256 + n]);
  o.z = f2b(w[(size_t)(d + 2) * 256 + n]);
  o.w = f2b(w[(size_t)(d + 3) * 256 + n]);
  *(ushort4*)(wt + (size_t)n * 1024 + d) = o;
}

// ---------------- k = x_n @ W[:, :128]  (M=65536, N=128, K=1024) -------------
__global__ __launch_bounds__(256) void kgemm(const u16* __restrict__ xn,
                                             const u16* __restrict__ wt,
                                             u16* __restrict__ ks) {
  __shared__ u16 As[128 * 32];
  __shared__ u16 Bs[128 * 32];
  const int t = threadIdx.x;
  const int lane = t & 63, w = t >> 6;
  const int wm = w >> 1, wn = w & 1;
  const int j0 = blockIdx.x * 128;
  const int g = lane >> 4, r16 = lane & 15;
  f32x4 acc[4][4] = {};
  for (int k0 = 0; k0 < 1024; k0 += 32) {
    __syncthreads();
#pragma unroll
    for (int i = 0; i < 2; ++i) {
      const int seg = i * 4 + w;
      const int off = seg * 1024 + lane * 16;  // linear LDS byte offset
      const int row = off >> 6;                // 64B per row (32 bf16)
      const int c = (off >> 4) & 3;            // 16B chunk in row
      const int sw = c ^ ((row >> 1) & 3);     // inverse-swizzled global source
      gload16(xn + ((size_t)(j0 + row)) * 1024 + k0 + sw * 8, (char*)As + seg * 1024);
      gload16(wt + ((size_t)row) * 1024 + k0 + sw * 8, (char*)Bs + seg * 1024);
    }
    __syncthreads();
    short8 a[4], bq[4];
#pragma unroll
    for (int mt = 0; mt < 4; ++mt) {
      const int row = wm * 64 + mt * 16 + r16;
      const int sw = g ^ ((row >> 1) & 3);
      a[mt] = *(const short8*)(As + row * 32 + sw * 8);
    }
#pragma unroll
    for (int nt = 0; nt < 4; ++nt) {
      const int row = wn * 64 + nt * 16 + r16;
      const int sw = g ^ ((row >> 1) & 3);
      bq[nt] = *(const short8*)(Bs + row * 32 + sw * 8);
    }
#pragma unroll
    for (int mt = 0; mt < 4; ++mt)
#pragma unroll
      for (int nt = 0; nt < 4; ++nt)
        acc[mt][nt] = __builtin_amdgcn_mfma_f32_16x16x32_bf16(a[mt], bq[nt], acc[mt][nt], 0, 0, 0);
  }
#pragma unroll
  for (int mt = 0; mt < 4; ++mt)
#pragma unroll
    for (int nt = 0; nt < 4; ++nt)
#pragma unroll
      for (int r = 0; r < 4; ++r) {
        const int j = j0 + wm * 64 + mt * 16 + g * 4 + r;
        const int n = wn * 64 + nt * 16 + r16;
        ks[(size_t)j * 128 + n] = f2b(acc[mt][nt][r]);
      }
}

// ---------------- sim + softmax -> attnb bf16 (single-barrier softmax) -------
__global__ __launch_bounds__(1024) void attn_kernel(const u16* __restrict__ qs,
                                                    const u16* __restrict__ ks,
                                                    u16* __restrict__ attnb) {
  const int orig = blockIdx.x;
  const int blk = (orig & 7) * 256 + (orig >> 3);  // bijective (2048 % 8 == 0)
  const int it = blk & 15, h = (blk >> 4) & 7, b = blk >> 7;
  const int i0 = it * 16;
  const int t = threadIdx.x;
  const int lane = t & 63, w = t >> 6;
  const int g = lane >> 4, r16 = lane & 15;
  __shared__ u16 Q[16 * 128];
  __shared__ float redm[256];
  __shared__ float reds[256];
  if (t < 256) {
    const int row = t >> 4, c = t & 15;
    const int sw = c ^ (row & 7);
    *(short8*)(Q + row * 128 + sw * 8) =
        *(const short8*)(qs + ((size_t)(b * 256 + i0 + row)) * 1024 + h * 128 + c * 8);
  }
  __syncthreads();
  short8 a[4];
#pragma unroll
  for (int kp = 0; kp < 4; ++kp) {
    const int c = kp * 4 + g;
    const int sw = c ^ (r16 & 7);
    a[kp] = *(const short8*)(Q + r16 * 128 + sw * 8);
  }
  const u16* kb = ks + (size_t)b * 4096 * 128;
  const int j0 = w * 256;
  f32x4 acc[16] = {};
#pragma unroll
  for (int kp = 0; kp < 4; ++kp) {
#pragma unroll
    for (int nt = 0; nt < 16; ++nt) {
      const short8 bv = *(const short8*)(kb + (size_t)(j0 + nt * 16 + r16) * 128 + kp * 32 + g * 8);
      acc[nt] = __builtin_amdgcn_mfma_f32_16x16x32_bf16(bv, a[kp], acc[nt], 0, 0, 0);
    }
  }
  float mx = acc[0][0];
#pragma unroll
  for (int nt = 0; nt < 16; ++nt)
#pragma unroll
    for (int r = 0; r < 4; ++r) mx = fmaxf(mx, acc[nt][r]);
  mx = fmaxf(mx, __shfl_xor(mx, 16));
  mx = fmaxf(mx, __shfl_xor(mx, 32));
  float sm = 0.f;
#pragma unroll
  for (int nt = 0; nt < 16; ++nt)
#pragma unroll
    for (int r = 0; r < 4; ++r) {
      const float p = __expf(acc[nt][r] - mx);
      acc[nt][r] = p;
      sm += p;
    }
  sm += __shfl_xor(sm, 16);
  sm += __shfl_xor(sm, 32);
  if (lane < 16) {
    redm[w * 16 + lane] = mx;
    reds[w * 16 + lane] = sm;
  }
  __syncthreads();  // single barrier
  float m = redm[r16];
#pragma unroll
  for (int w2 = 1; w2 < 16; ++w2) m = fmaxf(m, redm[w2 * 16 + r16]);
  float s = 0.f;
#pragma unroll
  for (int w2 = 0; w2 < 16; ++w2)
    s += reds[w2 * 16 + r16] * __expf(redm[w2 * 16 + r16] - m);
  const float f = __expf(mx - m) / s;  // folds rescale + normalize
#pragma unroll
  for (int nt = 0; nt < 16; ++nt) acc[nt] *= f;

  u16* brow = attnb + ((size_t)((b * 8 + h) * 256 + i0 + r16)) * 4096 + j0;
  const bool gb0 = (g & 1), gb1 = (g & 2);
#pragma unroll
  for (int q4 = 0; q4 < 4; ++q4) {
    uint2 X[4];
#pragma unroll
    for (int i = 0; i < 4; ++i) {
      const f32x4 v = acc[q4 * 4 + i];
      X[i] = make_uint2(cvtpk(v[0], v[1]), cvtpk(v[2], v[3]));
    }
#pragma unroll
    for (int k = 0; k < 2; ++k) {
      const uint2 aa = X[2 * k], bb = X[2 * k + 1];
      const uint2 sent = gb0 ? aa : bb;
      const uint2 recv = shflx2(sent, 16);
      X[2 * k] = gb0 ? recv : aa;
      X[2 * k + 1] = gb0 ? bb : recv;
    }
#pragma unroll
    for (int k = 0; k < 2; ++k) {
      const uint2 aa = X[k], bb = X[k + 2];
      const uint2 sent = gb1 ? aa : bb;
      const uint2 recv = shflx2(sent, 32);
      X[k] = gb1 ? recv : aa;
      X[k + 2] = gb1 ? bb : recv;
    }
    u16* bp = brow + q4 * 64 + g * 16;
    u32x4 o0 = {X[0].x, X[0].y, X[1].x, X[1].y};
    u32x4 o1 = {X[2].x, X[2].y, X[3].x, X[3].y};
    *(u32x4*)bp = o0;
    *(u32x4*)(bp + 8) = o1;
  }
}

// ---------------- out = attnb @ x_nT + BALANCED attn f32 side-write ----------
// R10/R12 schedule. EVERY block writes its own 64-row slice of the attn f32
// panel (rows [ft*64, ft*64+64)) — the A panel streams through all blocks'
// LDS identically, so the writer choice is free. Balanced store load (2 NT
// stores/thread/iter, uniform) removes the ft==0 straggler. vmcnt uniform:
// queue at wait = loads(t+1)[8] + stores(t)[2] + loads(t+2)[8] -> vmcnt(10).
__global__ __launch_bounds__(512, 2) void ogemm256(const u16* __restrict__ attnb,
                                                   const u16* __restrict__ xnt,
                                                   float* __restrict__ out,
                                                   float* __restrict__ attn) {
  extern __shared__ u16 S[];  // 128KB: A dbuf bytes [0,64K), B dbuf [64K,128K)
  const int orig = blockIdx.x;
  const int wid = (orig & 7) * 64 + (orig >> 3);  // XCD-chunked, bijective
  const int b = wid >> 5, ft = (wid >> 3) & 3, h = wid & 7;
  const int t = threadIdx.x;
  const int lane = t & 63, w = t >> 6;
  const int wm = w >> 2, wn = w & 3;
  const int g = lane >> 4, r16 = lane & 15;
  const u16* Ab = attnb + ((size_t)(b * 8 + h) * 256) * 4096;
  const u16* Bb = xnt + ((size_t)b * 1024 + ft * 256) * 4096;
  // balanced widen mapping: thread t -> row ft*64 + (t>>3), 16B chunk (t&7)
  const int wrow = ft * 64 + (t >> 3);
  const int wci = t & 7;
  float* wdst = attn + ((size_t)(b * 8 + h) * 256 + wrow) * 4096 + wci * 8;

  int srow[4], scol[4];
#pragma unroll
  for (int seg = 0; seg < 4; ++seg) {
    const int gi = seg * 512 + t;
    srow[seg] = gi >> 3;
    scol[seg] = (((gi & 7) ^ ((gi >> 3) & 7)) * 8);
  }
  const int wuni = w * 1024;

#define OSTAGE(buf, k0)                                                         \
  do {                                                                          \
    _Pragma("unroll") for (int seg = 0; seg < 4; ++seg)                         \
        gload16(Ab + (size_t)srow[seg] * 4096 + (k0) + scol[seg],               \
                (char*)S + (buf)*32768 + seg * 8192 + wuni);                    \
    _Pragma("unroll") for (int seg = 0; seg < 4; ++seg)                         \
        gload16(Bb + (size_t)srow[seg] * 4096 + (k0) + scol[seg],               \
                (char*)S + 65536 + (buf)*32768 + seg * 8192 + wuni);            \
  } while (0)

  f32x4 acc[8][4] = {};
  OSTAGE(0, 0);
  OSTAGE(1, 64);
  asm volatile("s_waitcnt vmcnt(8)" ::: "memory");  // tile0 done; tile1 flying
  __builtin_amdgcn_s_barrier();

  for (int t64 = 0; t64 < 64; ++t64) {
    const int buf = t64 & 1;
    const char* A0 = (const char*)S + buf * 32768;
    const char* B0 = (const char*)S + 65536 + buf * 32768;
    short8 af[8], bf[4];
    // ---- ks = 0 frags ----
#pragma unroll
    for (int mt = 0; mt < 8; ++mt) {
      const int row = wm * 128 + mt * 16 + r16;
      af[mt] = *(const short8*)(A0 + row * 128 + ((g ^ (row & 7)) * 16));
    }
#pragma unroll
    for (int nt = 0; nt < 4; ++nt) {
      const int row = wn * 64 + nt * 16 + r16;
      bf[nt] = *(const short8*)(B0 + row * 128 + ((g ^ (row & 7)) * 16));
    }
    asm volatile("s_waitcnt lgkmcnt(0)" ::: "memory");
    __builtin_amdgcn_sched_barrier(0);
    __builtin_amdgcn_s_setprio(1);
#pragma unroll
    for (int mt = 0; mt < 8; ++mt)
#pragma unroll
      for (int nt = 0; nt < 4; ++nt)
        acc[mt][nt] = __builtin_amdgcn_mfma_f32_16x16x32_bf16(af[mt], bf[nt], acc[mt][nt], 0, 0, 0);
    __builtin_amdgcn_s_setprio(0);
    // ---- ks = 1 frags + this block's widen slice read ----
#pragma unroll
    for (int mt = 0; mt < 8; ++mt) {
      const int row = wm * 128 + mt * 16 + r16;
      af[mt] = *(const short8*)(A0 + row * 128 + (((4 + g) ^ (row & 7)) * 16));
    }
#pragma unroll
    for (int nt = 0; nt < 4; ++nt) {
      const int row = wn * 64 + nt * 16 + r16;
      bf[nt] = *(const short8*)(B0 + row * 128 + (((4 + g) ^ (row & 7)) * 16));
    }
    const short8 wv = *(const short8*)(A0 + wrow * 128 + ((wci ^ (wrow & 7)) * 16));
    asm volatile("s_waitcnt lgkmcnt(0)" ::: "memory");
    __builtin_amdgcn_sched_barrier(0);
    {  // widen bf16->f32 (<<16, bit-exact vs MFMA input); lanes contiguous ->
       // full 64B lines per store instruction (8 lanes cover 256B of one row)
      f32x4 lo, hi;
#pragma unroll
      for (int e = 0; e < 4; ++e) {
        lo[e] = __uint_as_float(((u32)(u16)wv[e]) << 16);
        hi[e] = __uint_as_float(((u32)(u16)wv[4 + e]) << 16);
      }
      float* dst = wdst + t64 * 64;
      __builtin_nontemporal_store(lo, (f32x4*)dst);
      __builtin_nontemporal_store(hi, (f32x4*)(dst + 4));
      __builtin_amdgcn_sched_barrier(0);  // pin stores before barrier/OSTAGE
    }
    __builtin_amdgcn_s_barrier();  // all waves done reading buf -> restage ok
    if (t64 + 2 < 64) OSTAGE(buf, (t64 + 2) * 64);
    __builtin_amdgcn_s_setprio(1);
#pragma unroll
    for (int mt = 0; mt < 8; ++mt)
#pragma unroll
      for (int nt = 0; nt < 4; ++nt)
        acc[mt][nt] = __builtin_amdgcn_mfma_f32_16x16x32_bf16(af[mt], bf[nt], acc[mt][nt], 0, 0, 0);
    __builtin_amdgcn_s_setprio(0);
    if (t64 + 2 < 64) {
      asm volatile("s_waitcnt vmcnt(10)" ::: "memory");  // drain loads(t+1); keep stores(t)+loads(t+2)
    } else if (t64 == 62) {
      asm volatile("s_waitcnt vmcnt(0)" ::: "memory");   // drain loads(63)+stores
    }
    __builtin_amdgcn_s_barrier();
  }
#undef OSTAGE

  float* ob = out + (size_t)b * 2097152 + (size_t)h * 1024;
#pragma unroll
  for (int mt = 0; mt < 8; ++mt)
#pragma unroll
    for (int nt = 0; nt < 4; ++nt)
#pragma unroll
      for (int r = 0; r < 4; ++r) {
        const int i = wm * 128 + mt * 16 + g * 4 + r;
        const int f = ft * 256 + wn * 64 + nt * 16 + r16;
        ob[(size_t)i * 8192 + f] = acc[mt][nt][r];
      }
}

extern "C" void kernel_launch(void* const* d_in, const int* in_sizes, int n_in,
                              void* d_out, int out_size, void* d_ws, size_t ws_size,
                              hipStream_t stream) {
  const float* img_q = (const float*)d_in[0];
  const float* x = (const float*)d_in[1];
  const float* gamma_q = (const float*)d_in[2];
  const float* gamma_x = (const float*)d_in[3];
  const float* wkv = (const float*)d_in[4];

  float* out_f = (float*)d_out;
  float* attn_f = out_f + OUT_ELEMS;

  // Stashes aliasing not-yet-written d_out regions (all dead before overwrite):
  u16* xn = (u16*)attn_f;        // x_n bf16 [65536][1024], 128MB of attn region
  u16* qsb = (u16*)out_f;        // q bf16 (scaled) [16][256][1024], 8MB
  u16* wtb = qsb + 4194304;      // Wt bf16 [128][1024]
  u16* ksb = wtb + 131072;       // k bf16 [16][4096][128], 16MB
  u16* xnt = (u16*)d_ws;         // x_nT bf16 [16][1024][4096], 128MiB
  u16* attnb = xnt + 67108864;   // attn bf16 [16][8][256][4096], 256MiB

  if (ws_size < (size_t)402653184) return;  // need 384MiB (confirmed R2-R4)

  (void)hipFuncSetAttribute((const void*)ogemm256,
                            hipFuncAttributeMaxDynamicSharedMemorySize, 131072);

  ln_xpose<<<2048, 1024, 0, stream>>>(x, gamma_x, xn, xnt);
  ln_rows<<<4096, 256, 0, stream>>>(img_q, gamma_q, qsb, SCALE);
  cvt_w<<<128, 256, 0, stream>>>(wkv, wtb);
  kgemm<<<512, 256, 0, stream>>>(xn, wtb, ksb);
  attn_kernel<<<2048, 1024, 0, stream>>>(qsb, ksb, attnb);
  ogemm256<<<512, 512, 131072, stream>>>(attnb, xnt, out_f, attn_f);
}

// Round 17
// 810.827 us; speedup vs baseline: 1.0084x; 1.0084x over previous
//
#include <hip/hip_runtime.h>

typedef unsigned short u16;
typedef unsigned int u32;
typedef __attribute__((ext_vector_type(8))) short short8;
typedef __attribute__((ext_vector_type(4))) float f32x4;
typedef __attribute__((ext_vector_type(4))) unsigned int u32x4;

// Problem constants: B=16, N=256, T=4096, D=1024, H=8, DH=128
#define SCALE 0.08838834764831845f
#define OUT_ELEMS 33554432ull  // 16*256*8*1024

__device__ __forceinline__ u16 f2b(float f) {  // f32 -> bf16 RNE
  u32 u = __float_as_uint(f);
  u32 r = u + 0x7fffu + ((u >> 16) & 1u);
  return (u16)(r >> 16);
}

__device__ __forceinline__ u32 cvtpk(float lo, float hi) {  // 2 f32 -> packed bf16x2 (RNE)
  u32 r;
  asm("v_cvt_pk_bf16_f32 %0, %1, %2" : "=v"(r) : "v"(lo), "v"(hi));
  return r;
}

__device__ __forceinline__ void gload16(const void* g, void* l) {
  // async global->LDS, 16B per lane; LDS dest = wave-uniform base (+ lane*16 by HW)
  __builtin_amdgcn_global_load_lds((const __attribute__((address_space(1))) void*)g,
                                   (__attribute__((address_space(3))) void*)l, 16, 0, 0);
}

__device__ __forceinline__ uint2 shflx2(uint2 v, int m) {
  uint2 r;
  r.x = __shfl_xor(v.x, m, 64);
  r.y = __shfl_xor(v.y, m, 64);
  return r;
}

// ---------------- LayerNorm rows of length 1024 -> bf16 (scale folded) -------
__global__ __launch_bounds__(256) void ln_rows(const float* __restrict__ in,
                                               const float* __restrict__ gamma,
                                               u16* __restrict__ out, float scale) {
  const int row = blockIdx.x;
  const int t = threadIdx.x;
  const float4 v = *(const float4*)(in + (size_t)row * 1024 + t * 4);
  float s = v.x + v.y + v.z + v.w;
  float q = v.x * v.x + v.y * v.y + v.z * v.z + v.w * v.w;
#pragma unroll
  for (int m = 32; m; m >>= 1) {
    s += __shfl_down(s, m);
    q += __shfl_down(q, m);
  }
  __shared__ float red[8];
  const int w = t >> 6;
  if ((t & 63) == 0) { red[w] = s; red[4 + w] = q; }
  __syncthreads();
  s = red[0] + red[1] + red[2] + red[3];
  q = red[4] + red[5] + red[6] + red[7];
  const float mu = s * (1.0f / 1024.0f);
  const float var = q * (1.0f / 1024.0f) - mu * mu;
  const float rs = rsqrtf(var + 1e-5f) * scale;
  const float4 g = *(const float4*)(gamma + t * 4);
  ushort4 o;
  o.x = f2b((v.x - mu) * rs * g.x);
  o.y = f2b((v.y - mu) * rs * g.y);
  o.z = f2b((v.z - mu) * rs * g.z);
  o.w = f2b((v.w - mu) * rs * g.w);
  *(ushort4*)(out + (size_t)row * 1024 + t * 4) = o;
}

// ---------------- fused LN(x) + transpose: x -> xn (row-major) + xnt ---------
__global__ __launch_bounds__(1024) void ln_xpose(const float* __restrict__ in,
                                                 const float* __restrict__ gamma,
                                                 u16* __restrict__ xn,
                                                 u16* __restrict__ xnt) {
  __shared__ u16 tile[32][1024];  // 64KB; read side banks 2-way (free)
  const int blk = blockIdx.x;     // 2048 blocks
  const int b = blk >> 7;         // 128 blocks per batch
  const int jj0 = (blk & 127) * 32;
  const int t = threadIdx.x;
  const int lane = t & 63, w = t >> 6;
  const size_t j0 = (size_t)blk * 32;

  float4 gv[4];
#pragma unroll
  for (int k = 0; k < 4; ++k) gv[k] = *(const float4*)(gamma + k * 256 + lane * 4);

  float4 va[2][4];
  float mu[2], rs[2];
#pragma unroll
  for (int rr = 0; rr < 2; ++rr) {
    const int row = w * 2 + rr;
    const float* src = in + (j0 + row) * 1024;
    float s = 0.f, q = 0.f;
#pragma unroll
    for (int k = 0; k < 4; ++k) {
      const float4 v = *(const float4*)(src + k * 256 + lane * 4);
      va[rr][k] = v;
      s += v.x + v.y + v.z + v.w;
      q += v.x * v.x + v.y * v.y + v.z * v.z + v.w * v.w;
    }
#pragma unroll
    for (int m = 1; m < 64; m <<= 1) {
      s += __shfl_xor(s, m);
      q += __shfl_xor(q, m);
    }
    const float m_ = s * (1.0f / 1024.0f);
    mu[rr] = m_;
    rs[rr] = rsqrtf(q * (1.0f / 1024.0f) - m_ * m_ + 1e-5f);
  }
#pragma unroll
  for (int rr = 0; rr < 2; ++rr) {
    const int row = w * 2 + rr;
    u16* xrow = xn + (j0 + row) * 1024;
#pragma unroll
    for (int k = 0; k < 4; ++k) {
      const float4 v = va[rr][k];
      uint2 p;
      p.x = cvtpk((v.x - mu[rr]) * rs[rr] * gv[k].x, (v.y - mu[rr]) * rs[rr] * gv[k].y);
      p.y = cvtpk((v.z - mu[rr]) * rs[rr] * gv[k].z, (v.w - mu[rr]) * rs[rr] * gv[k].w);
      *(uint2*)(xrow + k * 256 + lane * 4) = p;
      *(uint2*)(&tile[row][k * 256 + lane * 4]) = p;
    }
  }
  __syncthreads();
  u32 o[16];
#pragma unroll
  for (int r = 0; r < 16; ++r)
    o[r] = (u32)tile[2 * r][t] | ((u32)tile[2 * r + 1][t] << 16);
  u16* dst = xnt + ((size_t)b * 1024 + t) * 4096 + jj0;
#pragma unroll
  for (int k = 0; k < 4; ++k) {
    u32x4 v = {o[4 * k + 0], o[4 * k + 1], o[4 * k + 2], o[4 * k + 3]};
    *(u32x4*)(dst + k * 8) = v;
  }
}

// ---------------- W_kv[:, :128] -> Wt bf16 [128][1024] -----------------------
__global__ __launch_bounds__(256) void cvt_w(const float* __restrict__ w, u16* __restrict__ wt) {
  const int n = blockIdx.x;  // 0..127
  const int t = threadIdx.x;
  const int d = t * 4;
  ushort4 o;
  o.x = f2b(w[(size_t)(d + 0) * 256 + n]);
  o.y = f2b(w[(size_t)(d + 1) * 256 + n]);
  o.z = f2b(w[(size_t)(d + 2) * 256 + n]);
  o.w = f2b(w[(size_t)(d + 3) * 256 + n]);
  *(ushort4*)(wt + (size_t)n * 1024 + d) = o;
}

// ---------------- k = x_n @ W[:, :128]  (M=65536, N=128, K=1024) -------------
__global__ __launch_bounds__(256) void kgemm(const u16* __restrict__ xn,
                                             const u16* __restrict__ wt,
                                             u16* __restrict__ ks) {
  __shared__ u16 As[128 * 32];
  __shared__ u16 Bs[128 * 32];
  const int t = threadIdx.x;
  const int lane = t & 63, w = t >> 6;
  const int wm = w >> 1, wn = w & 1;
  const int j0 = blockIdx.x * 128;
  const int g = lane >> 4, r16 = lane & 15;
  f32x4 acc[4][4] = {};
  for (int k0 = 0; k0 < 1024; k0 += 32) {
    __syncthreads();
#pragma unroll
    for (int i = 0; i < 2; ++i) {
      const int seg = i * 4 + w;
      const int off = seg * 1024 + lane * 16;  // linear LDS byte offset
      const int row = off >> 6;                // 64B per row (32 bf16)
      const int c = (off >> 4) & 3;            // 16B chunk in row
      const int sw = c ^ ((row >> 1) & 3);     // inverse-swizzled global source
      gload16(xn + ((size_t)(j0 + row)) * 1024 + k0 + sw * 8, (char*)As + seg * 1024);
      gload16(wt + ((size_t)row) * 1024 + k0 + sw * 8, (char*)Bs + seg * 1024);
    }
    __syncthreads();
    short8 a[4], bq[4];
#pragma unroll
    for (int mt = 0; mt < 4; ++mt) {
      const int row = wm * 64 + mt * 16 + r16;
      const int sw = g ^ ((row >> 1) & 3);
      a[mt] = *(const short8*)(As + row * 32 + sw * 8);
    }
#pragma unroll
    for (int nt = 0; nt < 4; ++nt) {
      const int row = wn * 64 + nt * 16 + r16;
      const int sw = g ^ ((row >> 1) & 3);
      bq[nt] = *(const short8*)(Bs + row * 32 + sw * 8);
    }
#pragma unroll
    for (int mt = 0; mt < 4; ++mt)
#pragma unroll
      for (int nt = 0; nt < 4; ++nt)
        acc[mt][nt] = __builtin_amdgcn_mfma_f32_16x16x32_bf16(a[mt], bq[nt], acc[mt][nt], 0, 0, 0);
  }
#pragma unroll
  for (int mt = 0; mt < 4; ++mt)
#pragma unroll
    for (int nt = 0; nt < 4; ++nt)
#pragma unroll
      for (int r = 0; r < 4; ++r) {
        const int j = j0 + wm * 64 + mt * 16 + g * 4 + r;
        const int n = wn * 64 + nt * 16 + r16;
        ks[(size_t)j * 128 + n] = f2b(acc[mt][nt][r]);
      }
}

// ---------------- sim + softmax -> attnb bf16 (single-barrier softmax) -------
// __launch_bounds__(1024, 1): 4 waves/SIMD -> 128 VGPR/wave so all 16 K-frag
// loads per kp-step stay in flight (at 64 VGPR the load stream serializes —
// R16 diagnosis: MfmaUtil 3%, VALUBusy 9%, nothing busy => latency-bound).
__global__ __launch_bounds__(1024, 1) void attn_kernel(const u16* __restrict__ qs,
                                                       const u16* __restrict__ ks,
                                                       u16* __restrict__ attnb) {
  const int orig = blockIdx.x;
  const int blk = (orig & 7) * 256 + (orig >> 3);  // bijective (2048 % 8 == 0)
  const int it = blk & 15, h = (blk >> 4) & 7, b = blk >> 7;
  const int i0 = it * 16;
  const int t = threadIdx.x;
  const int lane = t & 63, w = t >> 6;
  const int g = lane >> 4, r16 = lane & 15;
  __shared__ u16 Q[16 * 128];
  __shared__ float redm[256];
  __shared__ float reds[256];
  if (t < 256) {
    const int row = t >> 4, c = t & 15;
    const int sw = c ^ (row & 7);
    *(short8*)(Q + row * 128 + sw * 8) =
        *(const short8*)(qs + ((size_t)(b * 256 + i0 + row)) * 1024 + h * 128 + c * 8);
  }
  __syncthreads();
  short8 a[4];
#pragma unroll
  for (int kp = 0; kp < 4; ++kp) {
    const int c = kp * 4 + g;
    const int sw = c ^ (r16 & 7);
    a[kp] = *(const short8*)(Q + r16 * 128 + sw * 8);
  }
  const u16* kb = ks + (size_t)b * 4096 * 128;
  const int j0 = w * 256;
  f32x4 acc[16] = {};
#pragma unroll
  for (int kp = 0; kp < 4; ++kp) {
    short8 bv[16];
#pragma unroll
    for (int nt = 0; nt < 16; ++nt)
      bv[nt] = *(const short8*)(kb + (size_t)(j0 + nt * 16 + r16) * 128 + kp * 32 + g * 8);
#pragma unroll
    for (int nt = 0; nt < 16; ++nt)
      acc[nt] = __builtin_amdgcn_mfma_f32_16x16x32_bf16(bv[nt], a[kp], acc[nt], 0, 0, 0);
  }
  float mx = acc[0][0];
#pragma unroll
  for (int nt = 0; nt < 16; ++nt)
#pragma unroll
    for (int r = 0; r < 4; ++r) mx = fmaxf(mx, acc[nt][r]);
  mx = fmaxf(mx, __shfl_xor(mx, 16));
  mx = fmaxf(mx, __shfl_xor(mx, 32));
  float sm = 0.f;
#pragma unroll
  for (int nt = 0; nt < 16; ++nt)
#pragma unroll
    for (int r = 0; r < 4; ++r) {
      const float p = __expf(acc[nt][r] - mx);
      acc[nt][r] = p;
      sm += p;
    }
  sm += __shfl_xor(sm, 16);
  sm += __shfl_xor(sm, 32);
  if (lane < 16) {
    redm[w * 16 + lane] = mx;
    reds[w * 16 + lane] = sm;
  }
  __syncthreads();  // single barrier
  float m = redm[r16];
#pragma unroll
  for (int w2 = 1; w2 < 16; ++w2) m = fmaxf(m, redm[w2 * 16 + r16]);
  float s = 0.f;
#pragma unroll
  for (int w2 = 0; w2 < 16; ++w2)
    s += reds[w2 * 16 + r16] * __expf(redm[w2 * 16 + r16] - m);
  const float f = __expf(mx - m) / s;  // folds rescale + normalize
#pragma unroll
  for (int nt = 0; nt < 16; ++nt) acc[nt] *= f;

  u16* brow = attnb + ((size_t)((b * 8 + h) * 256 + i0 + r16)) * 4096 + j0;
  const bool gb0 = (g & 1), gb1 = (g & 2);
#pragma unroll
  for (int q4 = 0; q4 < 4; ++q4) {
    uint2 X[4];
#pragma unroll
    for (int i = 0; i < 4; ++i) {
      const f32x4 v = acc[q4 * 4 + i];
      X[i] = make_uint2(cvtpk(v[0], v[1]), cvtpk(v[2], v[3]));
    }
#pragma unroll
    for (int k = 0; k < 2; ++k) {
      const uint2 aa = X[2 * k], bb = X[2 * k + 1];
      const uint2 sent = gb0 ? aa : bb;
      const uint2 recv = shflx2(sent, 16);
      X[2 * k] = gb0 ? recv : aa;
      X[2 * k + 1] = gb0 ? bb : recv;
    }
#pragma unroll
    for (int k = 0; k < 2; ++k) {
      const uint2 aa = X[k], bb = X[k + 2];
      const uint2 sent = gb1 ? aa : bb;
      const uint2 recv = shflx2(sent, 32);
      X[k] = gb1 ? recv : aa;
      X[k + 2] = gb1 ? bb : recv;
    }
    u16* bp = brow + q4 * 64 + g * 16;
    u32x4 o0 = {X[0].x, X[0].y, X[1].x, X[1].y};
    u32x4 o1 = {X[2].x, X[2].y, X[3].x, X[3].y};
    *(u32x4*)bp = o0;
    *(u32x4*)(bp + 8) = o1;
  }
}

// ---------------- out = attnb @ x_nT + BALANCED attn f32 side-write ----------
__global__ __launch_bounds__(512, 2) void ogemm256(const u16* __restrict__ attnb,
                                                   const u16* __restrict__ xnt,
                                                   float* __restrict__ out,
                                                   float* __restrict__ attn) {
  extern __shared__ u16 S[];  // 128KB: A dbuf bytes [0,64K), B dbuf [64K,128K)
  const int orig = blockIdx.x;
  const int wid = (orig & 7) * 64 + (orig >> 3);  // XCD-chunked, bijective
  const int b = wid >> 5, ft = (wid >> 3) & 3, h = wid & 7;
  const int t = threadIdx.x;
  const int lane = t & 63, w = t >> 6;
  const int wm = w >> 2, wn = w & 3;
  const int g = lane >> 4, r16 = lane & 15;
  const u16* Ab = attnb + ((size_t)(b * 8 + h) * 256) * 4096;
  const u16* Bb = xnt + ((size_t)b * 1024 + ft * 256) * 4096;
  // balanced widen mapping: thread t -> row ft*64 + (t>>3), 16B chunk (t&7)
  const int wrow = ft * 64 + (t >> 3);
  const int wci = t & 7;
  float* wdst = attn + ((size_t)(b * 8 + h) * 256 + wrow) * 4096 + wci * 8;

  int srow[4], scol[4];
#pragma unroll
  for (int seg = 0; seg < 4; ++seg) {
    const int gi = seg * 512 + t;
    srow[seg] = gi >> 3;
    scol[seg] = (((gi & 7) ^ ((gi >> 3) & 7)) * 8);
  }
  const int wuni = w * 1024;

#define OSTAGE(buf, k0)                                                         \
  do {                                                                          \
    _Pragma("unroll") for (int seg = 0; seg < 4; ++seg)                         \
        gload16(Ab + (size_t)srow[seg] * 4096 + (k0) + scol[seg],               \
                (char*)S + (buf)*32768 + seg * 8192 + wuni);                    \
    _Pragma("unroll") for (int seg = 0; seg < 4; ++seg)                         \
        gload16(Bb + (size_t)srow[seg] * 4096 + (k0) + scol[seg],               \
                (char*)S + 65536 + (buf)*32768 + seg * 8192 + wuni);            \
  } while (0)

  f32x4 acc[8][4] = {};
  OSTAGE(0, 0);
  OSTAGE(1, 64);
  asm volatile("s_waitcnt vmcnt(8)" ::: "memory");  // tile0 done; tile1 flying
  __builtin_amdgcn_s_barrier();

  for (int t64 = 0; t64 < 64; ++t64) {
    const int buf = t64 & 1;
    const char* A0 = (const char*)S + buf * 32768;
    const char* B0 = (const char*)S + 65536 + buf * 32768;
    short8 af[8], bf[4];
    // ---- ks = 0 frags ----
#pragma unroll
    for (int mt = 0; mt < 8; ++mt) {
      const int row = wm * 128 + mt * 16 + r16;
      af[mt] = *(const short8*)(A0 + row * 128 + ((g ^ (row & 7)) * 16));
    }
#pragma unroll
    for (int nt = 0; nt < 4; ++nt) {
      const int row = wn * 64 + nt * 16 + r16;
      bf[nt] = *(const short8*)(B0 + row * 128 + ((g ^ (row & 7)) * 16));
    }
    asm volatile("s_waitcnt lgkmcnt(0)" ::: "memory");
    __builtin_amdgcn_sched_barrier(0);
    __builtin_amdgcn_s_setprio(1);
#pragma unroll
    for (int mt = 0; mt < 8; ++mt)
#pragma unroll
      for (int nt = 0; nt < 4; ++nt)
        acc[mt][nt] = __builtin_amdgcn_mfma_f32_16x16x32_bf16(af[mt], bf[nt], acc[mt][nt], 0, 0, 0);
    __builtin_amdgcn_s_setprio(0);
    // ---- ks = 1 frags + this block's widen slice read ----
#pragma unroll
    for (int mt = 0; mt < 8; ++mt) {
      const int row = wm * 128 + mt * 16 + r16;
      af[mt] = *(const short8*)(A0 + row * 128 + (((4 + g) ^ (row & 7)) * 16));
    }
#pragma unroll
    for (int nt = 0; nt < 4; ++nt) {
      const int row = wn * 64 + nt * 16 + r16;
      bf[nt] = *(const short8*)(B0 + row * 128 + (((4 + g) ^ (row & 7)) * 16));
    }
    const short8 wv = *(const short8*)(A0 + wrow * 128 + ((wci ^ (wrow & 7)) * 16));
    asm volatile("s_waitcnt lgkmcnt(0)" ::: "memory");
    __builtin_amdgcn_sched_barrier(0);
    {  // widen bf16->f32 (<<16, bit-exact vs MFMA input); lanes contiguous ->
       // full 64B lines per store instruction (8 lanes cover 256B of one row)
      f32x4 lo, hi;
#pragma unroll
      for (int e = 0; e < 4; ++e) {
        lo[e] = __uint_as_float(((u32)(u16)wv[e]) << 16);
        hi[e] = __uint_as_float(((u32)(u16)wv[4 + e]) << 16);
      }
      float* dst = wdst + t64 * 64;
      __builtin_nontemporal_store(lo, (f32x4*)dst);
      __builtin_nontemporal_store(hi, (f32x4*)(dst + 4));
      __builtin_amdgcn_sched_barrier(0);  // pin stores before barrier/OSTAGE
    }
    __builtin_amdgcn_s_barrier();  // all waves done reading buf -> restage ok
    if (t64 + 2 < 64) OSTAGE(buf, (t64 + 2) * 64);
    __builtin_amdgcn_s_setprio(1);
#pragma unroll
    for (int mt = 0; mt < 8; ++mt)
#pragma unroll
      for (int nt = 0; nt < 4; ++nt)
        acc[mt][nt] = __builtin_amdgcn_mfma_f32_16x16x32_bf16(af[mt], bf[nt], acc[mt][nt], 0, 0, 0);
    __builtin_amdgcn_s_setprio(0);
    if (t64 + 2 < 64) {
      asm volatile("s_waitcnt vmcnt(10)" ::: "memory");  // drain loads(t+1); keep stores(t)+loads(t+2)
    } else if (t64 == 62) {
      asm volatile("s_waitcnt vmcnt(0)" ::: "memory");   // drain loads(63)+stores
    }
    __builtin_amdgcn_s_barrier();
  }
#undef OSTAGE

  float* ob = out + (size_t)b * 2097152 + (size_t)h * 1024;
#pragma unroll
  for (int mt = 0; mt < 8; ++mt)
#pragma unroll
    for (int nt = 0; nt < 4; ++nt)
#pragma unroll
      for (int r = 0; r < 4; ++r) {
        const int i = wm * 128 + mt * 16 + g * 4 + r;
        const int f = ft * 256 + wn * 64 + nt * 16 + r16;
        ob[(size_t)i * 8192 + f] = acc[mt][nt][r];
      }
}

extern "C" void kernel_launch(void* const* d_in, const int* in_sizes, int n_in,
                              void* d_out, int out_size, void* d_ws, size_t ws_size,
                              hipStream_t stream) {
  const float* img_q = (const float*)d_in[0];
  const float* x = (const float*)d_in[1];
  const float* gamma_q = (const float*)d_in[2];
  const float* gamma_x = (const float*)d_in[3];
  const float* wkv = (const float*)d_in[4];

  float* out_f = (float*)d_out;
  float* attn_f = out_f + OUT_ELEMS;

  // Stashes aliasing not-yet-written d_out regions (all dead before overwrite):
  u16* xn = (u16*)attn_f;        // x_n bf16 [65536][1024], 128MB of attn region
  u16* qsb = (u16*)out_f;        // q bf16 (scaled) [16][256][1024], 8MB
  u16* wtb = qsb + 4194304;      // Wt bf16 [128][1024]
  u16* ksb = wtb + 131072;       // k bf16 [16][4096][128], 16MB
  u16* xnt = (u16*)d_ws;         // x_nT bf16 [16][1024][4096], 128MiB
  u16* attnb = xnt + 67108864;   // attn bf16 [16][8][256][4096], 256MiB

  if (ws_size < (size_t)402653184) return;  // need 384MiB (confirmed R2-R4)

  (void)hipFuncSetAttribute((const void*)ogemm256,
                            hipFuncAttributeMaxDynamicSharedMemorySize, 131072);

  ln_xpose<<<2048, 1024, 0, stream>>>(x, gamma_x, xn, xnt);
  ln_rows<<<4096, 256, 0, stream>>>(img_q, gamma_q, qsb, SCALE);
  cvt_w<<<128, 256, 0, stream>>>(wkv, wtb);
  kgemm<<<512, 256, 0, stream>>>(xn, wtb, ksb);
  attn_kernel<<<2048, 1024, 0, stream>>>(qsb, ksb, attnb);
  ogemm256<<<512, 512, 131072, stream>>>(attnb, xnt, out_f, attn_f);
}

// Round 18
// 713.063 us; speedup vs baseline: 1.1467x; 1.1371x over previous
//
#include <hip/hip_runtime.h>

typedef unsigned short u16;
typedef unsigned int u32;
typedef __attribute__((ext_vector_type(8))) short short8;
typedef __attribute__((ext_vector_type(4))) float f32x4;
typedef __attribute__((ext_vector_type(4))) unsigned int u32x4;

// Problem constants: B=16, N=256, T=4096, D=1024, H=8, DH=128
#define SCALE 0.08838834764831845f
#define OUT_ELEMS 33554432ull  // 16*256*8*1024

__device__ __forceinline__ u16 f2b(float f) {  // f32 -> bf16 RNE
  u32 u = __float_as_uint(f);
  u32 r = u + 0x7fffu + ((u >> 16) & 1u);
  return (u16)(r >> 16);
}

__device__ __forceinline__ u32 cvtpk(float lo, float hi) {  // 2 f32 -> packed bf16x2 (RNE)
  u32 r;
  asm("v_cvt_pk_bf16_f32 %0, %1, %2" : "=v"(r) : "v"(lo), "v"(hi));
  return r;
}

__device__ __forceinline__ void gload16(const void* g, void* l) {
  // async global->LDS, 16B per lane; LDS dest = wave-uniform base (+ lane*16 by HW)
  __builtin_amdgcn_global_load_lds((const __attribute__((address_space(1))) void*)g,
                                   (__attribute__((address_space(3))) void*)l, 16, 0, 0);
}

__device__ __forceinline__ uint2 shflx2(uint2 v, int m) {
  uint2 r;
  r.x = __shfl_xor(v.x, m, 64);
  r.y = __shfl_xor(v.y, m, 64);
  return r;
}

// ---------------- LayerNorm rows of length 1024 -> bf16 (scale folded) -------
__global__ __launch_bounds__(256) void ln_rows(const float* __restrict__ in,
                                               const float* __restrict__ gamma,
                                               u16* __restrict__ out, float scale) {
  const int row = blockIdx.x;
  const int t = threadIdx.x;
  const float4 v = *(const float4*)(in + (size_t)row * 1024 + t * 4);
  float s = v.x + v.y + v.z + v.w;
  float q = v.x * v.x + v.y * v.y + v.z * v.z + v.w * v.w;
#pragma unroll
  for (int m = 32; m; m >>= 1) {
    s += __shfl_down(s, m);
    q += __shfl_down(q, m);
  }
  __shared__ float red[8];
  const int w = t >> 6;
  if ((t & 63) == 0) { red[w] = s; red[4 + w] = q; }
  __syncthreads();
  s = red[0] + red[1] + red[2] + red[3];
  q = red[4] + red[5] + red[6] + red[7];
  const float mu = s * (1.0f / 1024.0f);
  const float var = q * (1.0f / 1024.0f) - mu * mu;
  const float rs = rsqrtf(var + 1e-5f) * scale;
  const float4 g = *(const float4*)(gamma + t * 4);
  ushort4 o;
  o.x = f2b((v.x - mu) * rs * g.x);
  o.y = f2b((v.y - mu) * rs * g.y);
  o.z = f2b((v.z - mu) * rs * g.z);
  o.w = f2b((v.w - mu) * rs * g.w);
  *(ushort4*)(out + (size_t)row * 1024 + t * 4) = o;
}

// ---------------- fused LN(x) + transpose: x -> xn (row-major) + xnt ---------
__global__ __launch_bounds__(1024) void ln_xpose(const float* __restrict__ in,
                                                 const float* __restrict__ gamma,
                                                 u16* __restrict__ xn,
                                                 u16* __restrict__ xnt) {
  __shared__ u16 tile[32][1024];  // 64KB; read side banks 2-way (free)
  const int blk = blockIdx.x;     // 2048 blocks
  const int b = blk >> 7;         // 128 blocks per batch
  const int jj0 = (blk & 127) * 32;
  const int t = threadIdx.x;
  const int lane = t & 63, w = t >> 6;
  const size_t j0 = (size_t)blk * 32;

  float4 gv[4];
#pragma unroll
  for (int k = 0; k < 4; ++k) gv[k] = *(const float4*)(gamma + k * 256 + lane * 4);

  float4 va[2][4];
  float mu[2], rs[2];
#pragma unroll
  for (int rr = 0; rr < 2; ++rr) {
    const int row = w * 2 + rr;
    const float* src = in + (j0 + row) * 1024;
    float s = 0.f, q = 0.f;
#pragma unroll
    for (int k = 0; k < 4; ++k) {
      const float4 v = *(const float4*)(src + k * 256 + lane * 4);
      va[rr][k] = v;
      s += v.x + v.y + v.z + v.w;
      q += v.x * v.x + v.y * v.y + v.z * v.z + v.w * v.w;
    }
#pragma unroll
    for (int m = 1; m < 64; m <<= 1) {
      s += __shfl_xor(s, m);
      q += __shfl_xor(q, m);
    }
    const float m_ = s * (1.0f / 1024.0f);
    mu[rr] = m_;
    rs[rr] = rsqrtf(q * (1.0f / 1024.0f) - m_ * m_ + 1e-5f);
  }
#pragma unroll
  for (int rr = 0; rr < 2; ++rr) {
    const int row = w * 2 + rr;
    u16* xrow = xn + (j0 + row) * 1024;
#pragma unroll
    for (int k = 0; k < 4; ++k) {
      const float4 v = va[rr][k];
      uint2 p;
      p.x = cvtpk((v.x - mu[rr]) * rs[rr] * gv[k].x, (v.y - mu[rr]) * rs[rr] * gv[k].y);
      p.y = cvtpk((v.z - mu[rr]) * rs[rr] * gv[k].z, (v.w - mu[rr]) * rs[rr] * gv[k].w);
      *(uint2*)(xrow + k * 256 + lane * 4) = p;
      *(uint2*)(&tile[row][k * 256 + lane * 4]) = p;
    }
  }
  __syncthreads();
  u32 o[16];
#pragma unroll
  for (int r = 0; r < 16; ++r)
    o[r] = (u32)tile[2 * r][t] | ((u32)tile[2 * r + 1][t] << 16);
  u16* dst = xnt + ((size_t)b * 1024 + t) * 4096 + jj0;
#pragma unroll
  for (int k = 0; k < 4; ++k) {
    u32x4 v = {o[4 * k + 0], o[4 * k + 1], o[4 * k + 2], o[4 * k + 3]};
    *(u32x4*)(dst + k * 8) = v;
  }
}

// ---------------- W_kv[:, :128] -> Wt bf16 [128][1024] -----------------------
__global__ __launch_bounds__(256) void cvt_w(const float* __restrict__ w, u16* __restrict__ wt) {
  const int n = blockIdx.x;  // 0..127
  const int t = threadIdx.x;
  const int d = t * 4;
  ushort4 o;
  o.x = f2b(w[(size_t)(d + 0) * 256 + n]);
  o.y = f2b(w[(size_t)(d + 1) * 256 + n]);
  o.z = f2b(w[(size_t)(d + 2) * 256 + n]);
  o.w = f2b(w[(size_t)(d + 3) * 256 + n]);
  *(ushort4*)(wt + (size_t)n * 1024 + d) = o;
}

// ---------------- k = x_n @ W[:, :128]  (M=65536, N=128, K=1024) -------------
__global__ __launch_bounds__(256) void kgemm(const u16* __restrict__ xn,
                                             const u16* __restrict__ wt,
                                             u16* __restrict__ ks) {
  __shared__ u16 As[128 * 32];
  __shared__ u16 Bs[128 * 32];
  const int t = threadIdx.x;
  const int lane = t & 63, w = t >> 6;
  const int wm = w >> 1, wn = w & 1;
  const int j0 = blockIdx.x * 128;
  const int g = lane >> 4, r16 = lane & 15;
  f32x4 acc[4][4] = {};
  for (int k0 = 0; k0 < 1024; k0 += 32) {
    __syncthreads();
#pragma unroll
    for (int i = 0; i < 2; ++i) {
      const int seg = i * 4 + w;
      const int off = seg * 1024 + lane * 16;  // linear LDS byte offset
      const int row = off >> 6;                // 64B per row (32 bf16)
      const int c = (off >> 4) & 3;            // 16B chunk in row
      const int sw = c ^ ((row >> 1) & 3);     // inverse-swizzled global source
      gload16(xn + ((size_t)(j0 + row)) * 1024 + k0 + sw * 8, (char*)As + seg * 1024);
      gload16(wt + ((size_t)row) * 1024 + k0 + sw * 8, (char*)Bs + seg * 1024);
    }
    __syncthreads();
    short8 a[4], bq[4];
#pragma unroll
    for (int mt = 0; mt < 4; ++mt) {
      const int row = wm * 64 + mt * 16 + r16;
      const int sw = g ^ ((row >> 1) & 3);
      a[mt] = *(const short8*)(As + row * 32 + sw * 8);
    }
#pragma unroll
    for (int nt = 0; nt < 4; ++nt) {
      const int row = wn * 64 + nt * 16 + r16;
      const int sw = g ^ ((row >> 1) & 3);
      bq[nt] = *(const short8*)(Bs + row * 32 + sw * 8);
    }
#pragma unroll
    for (int mt = 0; mt < 4; ++mt)
#pragma unroll
      for (int nt = 0; nt < 4; ++nt)
        acc[mt][nt] = __builtin_amdgcn_mfma_f32_16x16x32_bf16(a[mt], bq[nt], acc[mt][nt], 0, 0, 0);
  }
#pragma unroll
  for (int mt = 0; mt < 4; ++mt)
#pragma unroll
    for (int nt = 0; nt < 4; ++nt)
#pragma unroll
      for (int r = 0; r < 4; ++r) {
        const int j = j0 + wm * 64 + mt * 16 + g * 4 + r;
        const int n = wn * 64 + nt * 16 + r16;
        ks[(size_t)j * 128 + n] = f2b(acc[mt][nt][r]);
      }
}

// ---------------- sim + softmax -> attnb bf16 (async LDS-staged K) -----------
// Per-wave barrier-free pipeline: K slice staged in 16 groups (64 rows x 32
// cols = 4 x gload16, pre-swizzled per-lane source), double-buffered 8KB/wave
// private LDS. vmcnt queue holds the in-flight loads (zero VGPR cost) —
// replaces the VGPR-bound bv[16] batch (R17: capped at 128 VGPR/wave).
// Accumulation order identical (kp-major, nt ascending) -> bit-identical.
__global__ __launch_bounds__(1024, 1) void attn_kernel(const u16* __restrict__ qs,
                                                       const u16* __restrict__ ks,
                                                       u16* __restrict__ attnb) {
  extern __shared__ char KS[];  // 128KB: wave w -> [w*8192, w*8192+8192)
  const int orig = blockIdx.x;
  const int blk = (orig & 7) * 256 + (orig >> 3);  // bijective (2048 % 8 == 0)
  const int it = blk & 15, h = (blk >> 4) & 7, b = blk >> 7;
  const int i0 = it * 16;
  const int t = threadIdx.x;
  const int lane = t & 63, w = t >> 6;
  const int gq = lane >> 4, r16 = lane & 15;
  __shared__ u16 Q[16 * 128];
  __shared__ float redm[256];
  __shared__ float reds[256];
  if (t < 256) {
    const int row = t >> 4, c = t & 15;
    const int sw = c ^ (row & 7);
    *(short8*)(Q + row * 128 + sw * 8) =
        *(const short8*)(qs + ((size_t)(b * 256 + i0 + row)) * 1024 + h * 128 + c * 8);
  }
  __syncthreads();
  short8 a[4];
#pragma unroll
  for (int kp = 0; kp < 4; ++kp) {
    const int c = kp * 4 + gq;
    const int sw = c ^ (r16 & 7);
    a[kp] = *(const short8*)(Q + r16 * 128 + sw * 8);
  }
  const u16* kb = ks + (size_t)b * 4096 * 128;
  const int j0 = w * 256;
  // staging source (per-lane, inverse-swizzled): instr i covers rows i*16+(lane>>2)
  const int srow = lane >> 2;                       // 0..15 within 16-row block
  const int scol = ((lane & 3) ^ (srow & 3)) * 8;   // u16 offset of 16B chunk
  char* wbuf = KS + w * 8192;

#define STAGEK(gg)                                                                \
  do {                                                                            \
    const int kp_ = (gg) >> 2, q_ = (gg)&3;                                       \
    const u16* s0 = kb + (size_t)(j0 + q_ * 64 + srow) * 128 + kp_ * 32 + scol;   \
    char* d0 = wbuf + ((gg)&1) * 4096;                                            \
    gload16(s0, d0);                                                              \
    gload16(s0 + 2048, d0 + 1024);                                                \
    gload16(s0 + 4096, d0 + 2048);                                                \
    gload16(s0 + 6144, d0 + 3072);                                                \
  } while (0)

  f32x4 acc[16] = {};
  STAGEK(0);
  const int rb = r16 * 64 + ((gq ^ (r16 & 3)) * 16);  // frag byte offset in 1KB row-block
#pragma unroll
  for (int gg = 0; gg < 16; ++gg) {
    if (gg + 1 < 16) STAGEK(gg + 1);
    if (gg + 1 < 16)
      asm volatile("s_waitcnt vmcnt(4)" ::: "memory");  // group gg landed; gg+1 flying
    else
      asm volatile("s_waitcnt vmcnt(0)" ::: "memory");
    __builtin_amdgcn_sched_barrier(0);
    const char* buf = wbuf + (gg & 1) * 4096;
    short8 bv[4];
#pragma unroll
    for (int i = 0; i < 4; ++i) bv[i] = *(const short8*)(buf + i * 1024 + rb);
    asm volatile("s_waitcnt lgkmcnt(0)" ::: "memory");
    __builtin_amdgcn_sched_barrier(0);
    const int kp = gg >> 2, q = gg & 3;
#pragma unroll
    for (int i = 0; i < 4; ++i)
      acc[q * 4 + i] = __builtin_amdgcn_mfma_f32_16x16x32_bf16(bv[i], a[kp], acc[q * 4 + i], 0, 0, 0);
  }
#undef STAGEK

  float mx = acc[0][0];
#pragma unroll
  for (int nt = 0; nt < 16; ++nt)
#pragma unroll
    for (int r = 0; r < 4; ++r) mx = fmaxf(mx, acc[nt][r]);
  mx = fmaxf(mx, __shfl_xor(mx, 16));
  mx = fmaxf(mx, __shfl_xor(mx, 32));
  float sm = 0.f;
#pragma unroll
  for (int nt = 0; nt < 16; ++nt)
#pragma unroll
    for (int r = 0; r < 4; ++r) {
      const float p = __expf(acc[nt][r] - mx);
      acc[nt][r] = p;
      sm += p;
    }
  sm += __shfl_xor(sm, 16);
  sm += __shfl_xor(sm, 32);
  if (lane < 16) {
    redm[w * 16 + lane] = mx;
    reds[w * 16 + lane] = sm;
  }
  __syncthreads();  // single barrier
  float m = redm[r16];
#pragma unroll
  for (int w2 = 1; w2 < 16; ++w2) m = fmaxf(m, redm[w2 * 16 + r16]);
  float s = 0.f;
#pragma unroll
  for (int w2 = 0; w2 < 16; ++w2)
    s += reds[w2 * 16 + r16] * __expf(redm[w2 * 16 + r16] - m);
  const float f = __expf(mx - m) / s;  // folds rescale + normalize
#pragma unroll
  for (int nt = 0; nt < 16; ++nt) acc[nt] *= f;

  u16* brow = attnb + ((size_t)((b * 8 + h) * 256 + i0 + r16)) * 4096 + j0;
  const bool gb0 = (gq & 1), gb1 = (gq & 2);
#pragma unroll
  for (int q4 = 0; q4 < 4; ++q4) {
    uint2 X[4];
#pragma unroll
    for (int i = 0; i < 4; ++i) {
      const f32x4 v = acc[q4 * 4 + i];
      X[i] = make_uint2(cvtpk(v[0], v[1]), cvtpk(v[2], v[3]));
    }
#pragma unroll
    for (int k = 0; k < 2; ++k) {
      const uint2 aa = X[2 * k], bb = X[2 * k + 1];
      const uint2 sent = gb0 ? aa : bb;
      const uint2 recv = shflx2(sent, 16);
      X[2 * k] = gb0 ? recv : aa;
      X[2 * k + 1] = gb0 ? bb : recv;
    }
#pragma unroll
    for (int k = 0; k < 2; ++k) {
      const uint2 aa = X[k], bb = X[k + 2];
      const uint2 sent = gb1 ? aa : bb;
      const uint2 recv = shflx2(sent, 32);
      X[k] = gb1 ? recv : aa;
      X[k + 2] = gb1 ? bb : recv;
    }
    u16* bp = brow + q4 * 64 + gq * 16;
    u32x4 o0 = {X[0].x, X[0].y, X[1].x, X[1].y};
    u32x4 o1 = {X[2].x, X[2].y, X[3].x, X[3].y};
    *(u32x4*)bp = o0;
    *(u32x4*)(bp + 8) = o1;
  }
}

// ---------------- out = attnb @ x_nT + BALANCED attn f32 side-write ----------
__global__ __launch_bounds__(512, 2) void ogemm256(const u16* __restrict__ attnb,
                                                   const u16* __restrict__ xnt,
                                                   float* __restrict__ out,
                                                   float* __restrict__ attn) {
  extern __shared__ u16 S[];  // 128KB: A dbuf bytes [0,64K), B dbuf [64K,128K)
  const int orig = blockIdx.x;
  const int wid = (orig & 7) * 64 + (orig >> 3);  // XCD-chunked, bijective
  const int b = wid >> 5, ft = (wid >> 3) & 3, h = wid & 7;
  const int t = threadIdx.x;
  const int lane = t & 63, w = t >> 6;
  const int wm = w >> 2, wn = w & 3;
  const int g = lane >> 4, r16 = lane & 15;
  const u16* Ab = attnb + ((size_t)(b * 8 + h) * 256) * 4096;
  const u16* Bb = xnt + ((size_t)b * 1024 + ft * 256) * 4096;
  const int wrow = ft * 64 + (t >> 3);
  const int wci = t & 7;
  float* wdst = attn + ((size_t)(b * 8 + h) * 256 + wrow) * 4096 + wci * 8;

  int srow[4], scol[4];
#pragma unroll
  for (int seg = 0; seg < 4; ++seg) {
    const int gi = seg * 512 + t;
    srow[seg] = gi >> 3;
    scol[seg] = (((gi & 7) ^ ((gi >> 3) & 7)) * 8);
  }
  const int wuni = w * 1024;

#define OSTAGE(buf, k0)                                                         \
  do {                                                                          \
    _Pragma("unroll") for (int seg = 0; seg < 4; ++seg)                         \
        gload16(Ab + (size_t)srow[seg] * 4096 + (k0) + scol[seg],               \
                (char*)S + (buf)*32768 + seg * 8192 + wuni);                    \
    _Pragma("unroll") for (int seg = 0; seg < 4; ++seg)                         \
        gload16(Bb + (size_t)srow[seg] * 4096 + (k0) + scol[seg],               \
                (char*)S + 65536 + (buf)*32768 + seg * 8192 + wuni);            \
  } while (0)

  f32x4 acc[8][4] = {};
  OSTAGE(0, 0);
  OSTAGE(1, 64);
  asm volatile("s_waitcnt vmcnt(8)" ::: "memory");  // tile0 done; tile1 flying
  __builtin_amdgcn_s_barrier();

  for (int t64 = 0; t64 < 64; ++t64) {
    const int buf = t64 & 1;
    const char* A0 = (const char*)S + buf * 32768;
    const char* B0 = (const char*)S + 65536 + buf * 32768;
    short8 af[8], bf[4];
    // ---- ks = 0 frags ----
#pragma unroll
    for (int mt = 0; mt < 8; ++mt) {
      const int row = wm * 128 + mt * 16 + r16;
      af[mt] = *(const short8*)(A0 + row * 128 + ((g ^ (row & 7)) * 16));
    }
#pragma unroll
    for (int nt = 0; nt < 4; ++nt) {
      const int row = wn * 64 + nt * 16 + r16;
      bf[nt] = *(const short8*)(B0 + row * 128 + ((g ^ (row & 7)) * 16));
    }
    asm volatile("s_waitcnt lgkmcnt(0)" ::: "memory");
    __builtin_amdgcn_sched_barrier(0);
    __builtin_amdgcn_s_setprio(1);
#pragma unroll
    for (int mt = 0; mt < 8; ++mt)
#pragma unroll
      for (int nt = 0; nt < 4; ++nt)
        acc[mt][nt] = __builtin_amdgcn_mfma_f32_16x16x32_bf16(af[mt], bf[nt], acc[mt][nt], 0, 0, 0);
    __builtin_amdgcn_s_setprio(0);
    // ---- ks = 1 frags + this block's widen slice read ----
#pragma unroll
    for (int mt = 0; mt < 8; ++mt) {
      const int row = wm * 128 + mt * 16 + r16;
      af[mt] = *(const short8*)(A0 + row * 128 + (((4 + g) ^ (row & 7)) * 16));
    }
#pragma unroll
    for (int nt = 0; nt < 4; ++nt) {
      const int row = wn * 64 + nt * 16 + r16;
      bf[nt] = *(const short8*)(B0 + row * 128 + (((4 + g) ^ (row & 7)) * 16));
    }
    const short8 wv = *(const short8*)(A0 + wrow * 128 + ((wci ^ (wrow & 7)) * 16));
    asm volatile("s_waitcnt lgkmcnt(0)" ::: "memory");
    __builtin_amdgcn_sched_barrier(0);
    {
      f32x4 lo, hi;
#pragma unroll
      for (int e = 0; e < 4; ++e) {
        lo[e] = __uint_as_float(((u32)(u16)wv[e]) << 16);
        hi[e] = __uint_as_float(((u32)(u16)wv[4 + e]) << 16);
      }
      float* dst = wdst + t64 * 64;
      __builtin_nontemporal_store(lo, (f32x4*)dst);
      __builtin_nontemporal_store(hi, (f32x4*)(dst + 4));
      __builtin_amdgcn_sched_barrier(0);  // pin stores before barrier/OSTAGE
    }
    __builtin_amdgcn_s_barrier();  // all waves done reading buf -> restage ok
    if (t64 + 2 < 64) OSTAGE(buf, (t64 + 2) * 64);
    __builtin_amdgcn_s_setprio(1);
#pragma unroll
    for (int mt = 0; mt < 8; ++mt)
#pragma unroll
      for (int nt = 0; nt < 4; ++nt)
        acc[mt][nt] = __builtin_amdgcn_mfma_f32_16x16x32_bf16(af[mt], bf[nt], acc[mt][nt], 0, 0, 0);
    __builtin_amdgcn_s_setprio(0);
    if (t64 + 2 < 64) {
      asm volatile("s_waitcnt vmcnt(10)" ::: "memory");  // drain loads(t+1); keep stores(t)+loads(t+2)
    } else if (t64 == 62) {
      asm volatile("s_waitcnt vmcnt(0)" ::: "memory");   // drain loads(63)+stores
    }
    __builtin_amdgcn_s_barrier();
  }
#undef OSTAGE

  float* ob = out + (size_t)b * 2097152 + (size_t)h * 1024;
#pragma unroll
  for (int mt = 0; mt < 8; ++mt)
#pragma unroll
    for (int nt = 0; nt < 4; ++nt)
#pragma unroll
      for (int r = 0; r < 4; ++r) {
        const int i = wm * 128 + mt * 16 + g * 4 + r;
        const int f = ft * 256 + wn * 64 + nt * 16 + r16;
        ob[(size_t)i * 8192 + f] = acc[mt][nt][r];
      }
}

extern "C" void kernel_launch(void* const* d_in, const int* in_sizes, int n_in,
                              void* d_out, int out_size, void* d_ws, size_t ws_size,
                              hipStream_t stream) {
  const float* img_q = (const float*)d_in[0];
  const float* x = (const float*)d_in[1];
  const float* gamma_q = (const float*)d_in[2];
  const float* gamma_x = (const float*)d_in[3];
  const float* wkv = (const float*)d_in[4];

  float* out_f = (float*)d_out;
  float* attn_f = out_f + OUT_ELEMS;

  // Stashes aliasing not-yet-written d_out regions (all dead before overwrite):
  u16* xn = (u16*)attn_f;        // x_n bf16 [65536][1024], 128MB of attn region
  u16* qsb = (u16*)out_f;        // q bf16 (scaled) [16][256][1024], 8MB
  u16* wtb = qsb + 4194304;      // Wt bf16 [128][1024]
  u16* ksb = wtb + 131072;       // k bf16 [16][4096][128], 16MB
  u16* xnt = (u16*)d_ws;         // x_nT bf16 [16][1024][4096], 128MiB
  u16* attnb = xnt + 67108864;   // attn bf16 [16][8][256][4096], 256MiB

  if (ws_size < (size_t)402653184) return;  // need 384MiB (confirmed R2-R4)

  (void)hipFuncSetAttribute((const void*)ogemm256,
                            hipFuncAttributeMaxDynamicSharedMemorySize, 131072);
  (void)hipFuncSetAttribute((const void*)attn_kernel,
                            hipFuncAttributeMaxDynamicSharedMemorySize, 131072);

  ln_xpose<<<2048, 1024, 0, stream>>>(x, gamma_x, xn, xnt);
  ln_rows<<<4096, 256, 0, stream>>>(img_q, gamma_q, qsb, SCALE);
  cvt_w<<<128, 256, 0, stream>>>(wkv, wtb);
  kgemm<<<512, 256, 0, stream>>>(xn, wtb, ksb);
  attn_kernel<<<2048, 1024, 131072, stream>>>(qsb, ksb, attnb);
  ogemm256<<<512, 512, 131072, stream>>>(attnb, xnt, out_f, attn_f);
}